// Round 1
// baseline (1178.053 us; speedup 1.0000x reference)
//
#include <hip/hip_runtime.h>
#include <cstdint>
#include <cstddef>

// Problem constants
#define N_TOK 4096
#define E_DIM 2048
#define NH    16
#define DH    128
#define KEXP  4
#define CAPN  1280
#define SCALE_QK 0.08838834764831845f
#define NEG_BIG -1e30f

typedef __attribute__((ext_vector_type(4))) float f32x4;
typedef __attribute__((ext_vector_type(8))) short s16x8;

__device__ __forceinline__ float bf2f(unsigned short u){
  union{unsigned int i; float fl;} c; c.i = ((unsigned int)u)<<16; return c.fl;
}
__device__ __forceinline__ unsigned short f2bf(float x){
  union{float fl; unsigned int i;} c; c.fl=x;
  return (unsigned short)((c.i + 0x7FFFu + ((c.i>>16)&1u))>>16);
}
// inline-asm MFMA: avoids builtin operand-type (short8 vs bf16x8) ambiguity.
__device__ __forceinline__ f32x4 mfma_bf16(s16x8 a, s16x8 b, f32x4 c){
  asm("v_mfma_f32_16x16x32_bf16 %0, %1, %2, %0" : "+v"(c) : "v"(a), "v"(b));
  return c;
}

// ---------------- conversions ----------------
__global__ __launch_bounds__(256) void conv_x_kernel(const float* __restrict__ x,
    unsigned short* __restrict__ hi, unsigned short* __restrict__ lo, int n4){
  int idx = blockIdx.x*256 + threadIdx.x;
  if (idx >= n4) return;
  float4 v = ((const float4*)x)[idx];
  float ar[4] = {v.x, v.y, v.z, v.w};
  union{ unsigned short u[4]; uint2 q; } H, L;
  #pragma unroll
  for(int i=0;i<4;i++){
    unsigned short h = f2bf(ar[i]);
    H.u[i] = h;
    L.u[i] = f2bf(ar[i] - bf2f(h));
  }
  ((uint2*)hi)[idx] = H.q;
  ((uint2*)lo)[idx] = L.q;
}

// transpose + f32->bf16 (optionally also lo residual). W[R][C] -> T[C][R]
__global__ __launch_bounds__(256) void tconv_kernel(const float* __restrict__ W,
    unsigned short* __restrict__ Thi, unsigned short* __restrict__ Tlo, int R, int C){
  __shared__ float t[32][33];
  int tx = threadIdx.x, ty = threadIdx.y;   // (32,8)
  int c0 = blockIdx.x*32, r0 = blockIdx.y*32;
  #pragma unroll
  for(int i=0;i<4;i++){
    int r = r0 + ty + i*8;
    t[ty+i*8][tx] = W[(size_t)r*C + c0 + tx];
  }
  __syncthreads();
  #pragma unroll
  for(int i=0;i<4;i++){
    int c = c0 + ty + i*8;
    float v = t[tx][ty+i*8];
    size_t o = (size_t)c*R + r0 + tx;
    unsigned short h = f2bf(v);
    Thi[o] = h;
    if (Tlo) Tlo[o] = f2bf(v - bf2f(h));
  }
}

// ---------------- bf16 MFMA GEMM: C[M][N] = A[M][K] * Bt[N][K]^T ----------------
template<int ACCUM, int OUTBF>
__global__ __launch_bounds__(256) void gemm_kernel(const unsigned short* __restrict__ A,
    const unsigned short* __restrict__ Bt, void* __restrict__ Cp, int N, int Kd){
  __shared__ __align__(16) unsigned short As[128][72];
  __shared__ __align__(16) unsigned short Bs[128][72];
  const int mb = blockIdx.y, nb = blockIdx.x;
  const int tid = threadIdx.x;
  const int lane = tid & 63, w = tid >> 6;
  const int g = lane >> 4, r16 = lane & 15;
  const int wm = w >> 1, wn = w & 1;
  f32x4 acc[4][4];
  #pragma unroll
  for(int i=0;i<4;i++)
    #pragma unroll
    for(int j=0;j<4;j++) acc[i][j] = f32x4{0.f,0.f,0.f,0.f};
  const unsigned short* Ab = A  + (size_t)mb*128*Kd;
  const unsigned short* Bb = Bt + (size_t)nb*128*Kd;
  for(int k0=0;k0<Kd;k0+=64){
    __syncthreads();
    #pragma unroll
    for(int i=0;i<4;i++){
      int c = tid + i*256;
      int row = c >> 3, kc = (c&7)*8;
      *(uint4*)&As[row][kc] = *(const uint4*)(Ab + (size_t)row*Kd + k0 + kc);
      *(uint4*)&Bs[row][kc] = *(const uint4*)(Bb + (size_t)row*Kd + k0 + kc);
    }
    __syncthreads();
    #pragma unroll
    for(int ks=0;ks<2;ks++){
      s16x8 af[4], bfr[4];
      #pragma unroll
      for(int f2=0;f2<4;f2++){
        af[f2]  = *(const s16x8*)&As[wm*64 + f2*16 + r16][ks*32 + 8*g];
        bfr[f2] = *(const s16x8*)&Bs[wn*64 + f2*16 + r16][ks*32 + 8*g];
      }
      #pragma unroll
      for(int fm=0;fm<4;fm++)
        #pragma unroll
        for(int fn=0;fn<4;fn++)
          acc[fm][fn] = mfma_bf16(af[fm], bfr[fn], acc[fm][fn]);
    }
  }
  const int rowb = mb*128 + wm*64, colb = nb*128 + wn*64;
  #pragma unroll
  for(int fm=0;fm<4;fm++)
    #pragma unroll
    for(int fn=0;fn<4;fn++)
      #pragma unroll
      for(int r=0;r<4;r++){
        int rr = rowb + fm*16 + 4*g + r;
        int cc = colb + fn*16 + r16;
        size_t o = (size_t)rr*N + cc;
        float v = acc[fm][fn][r];
        if (OUTBF)        ((unsigned short*)Cp)[o] = f2bf(v);
        else if (ACCUM)   ((float*)Cp)[o] += v;
        else              ((float*)Cp)[o] = v;
      }
}

// ---------------- router pointwise ----------------
__global__ __launch_bounds__(256) void gelu_kernel(float* __restrict__ h, const float* __restrict__ br1){
  int idx = blockIdx.x*256 + threadIdx.x;   // exact 4096*1024
  float v = h[idx] + br1[idx & 1023];
  h[idx] = 0.5f*v*(1.0f + erff(v*0.70710678118654752f));
}

__global__ __launch_bounds__(256) void scores_kernel(const float* __restrict__ h,
    const float* __restrict__ Wr2, const float* __restrict__ br2,
    float* __restrict__ scores, float* __restrict__ tokmax){
  int tid = threadIdx.x;
  int n = blockIdx.x*4 + (tid>>6);
  int lane = tid & 63;
  const float* hr = h + (size_t)n*1024;
  float s0=0,s1=0,s2=0,s3=0;
  #pragma unroll
  for(int i=0;i<16;i++){
    int j = lane + i*64;
    float hv = hr[j];
    float4 wv = *(const float4*)(Wr2 + (size_t)j*4);
    s0 += hv*wv.x; s1 += hv*wv.y; s2 += hv*wv.z; s3 += hv*wv.w;
  }
  #pragma unroll
  for(int m=32;m>=1;m>>=1){
    s0 += __shfl_xor(s0,m); s1 += __shfl_xor(s1,m);
    s2 += __shfl_xor(s2,m); s3 += __shfl_xor(s3,m);
  }
  if (lane==0){
    s0+=br2[0]; s1+=br2[1]; s2+=br2[2]; s3+=br2[3];
    scores[n*4+0]=s0; scores[n*4+1]=s1; scores[n*4+2]=s2; scores[n*4+3]=s3;
    tokmax[n]=fmaxf(fmaxf(s0,s1),fmaxf(s2,s3));
  }
}

__global__ __launch_bounds__(1024) void aux_kernel(const float* __restrict__ tokmax, float* __restrict__ out_aux){
  __shared__ float red[1024];
  int t = threadIdx.x;
  red[t] = tokmax[t] + tokmax[t+1024] + tokmax[t+2048] + tokmax[t+3072];
  __syncthreads();
  for(int k=512;k>=1;k>>=1){ if(t<k) red[t]+=red[t+k]; __syncthreads(); }
  if (t==0) out_aux[0] = -red[0]/4096.0f;
}

// ---------------- exact top-k (bitonic sort of 4096 per expert) ----------------
__global__ __launch_bounds__(1024) void topk_kernel(const float* __restrict__ scores,
    int* __restrict__ topk_idx, float* __restrict__ sel_w, int* __restrict__ rank_of){
  __shared__ float sv[4096];
  __shared__ int   si[4096];
  __shared__ float red[1024];
  int e = blockIdx.x, t = threadIdx.x;
  for(int i=t;i<4096;i+=1024){ sv[i]=scores[i*4+e]; si[i]=i; }
  __syncthreads();
  // sort descending by value, ties -> lower index first (matches jax.lax.top_k)
  for(int k=2;k<=4096;k<<=1){
    for(int j=k>>1;j>0;j>>=1){
      for(int i=t;i<4096;i+=1024){
        int ixj = i^j;
        if (ixj>i){
          float vi=sv[i], vj=sv[ixj];
          int ii=si[i], ij=si[ixj];
          bool jGreater = (vj>vi) || (vj==vi && ij<ii);
          bool asc = (i&k)==0;
          if (asc ? jGreater : !jGreater){
            sv[i]=vj; sv[ixj]=vi; si[i]=ij; si[ixj]=ii;
          }
        }
      }
      __syncthreads();
    }
  }
  for(int i=t;i<4096;i+=1024) rank_of[e*4096+i] = -1;
  __syncthreads();
  for(int r=t;r<CAPN;r+=1024){
    int tok = si[r];
    topk_idx[e*CAPN+r] = tok;
    rank_of[e*4096+tok] = r;
  }
  float mx = sv[0];
  float part = 0.f;
  for(int r=t;r<CAPN;r+=1024) part += expf(sv[r]-mx);
  red[t]=part; __syncthreads();
  for(int k=512;k>=1;k>>=1){ if(t<k) red[t]+=red[t+k]; __syncthreads(); }
  float denom = red[0];
  for(int r=t;r<CAPN;r+=1024) sel_w[e*CAPN+r] = expf(sv[r]-mx)/denom;
}

// ---------------- RoPE tables [CAPN][64] ----------------
__global__ __launch_bounds__(256) void rope_kernel(float* __restrict__ cosT, float* __restrict__ sinT){
  int idx = blockIdx.x*256 + threadIdx.x;   // exact 1280*64
  int p = idx>>6, dm = idx&63;
  float inv = powf(10000.0f, -(float)dm/64.0f);
  float ang = (float)p*inv;
  cosT[idx]=cosf(ang);
  sinT[idx]=sinf(ang);
}

// ---------------- gathered causal flash attention per (qtile, head, expert) ----------------
__global__ __launch_bounds__(256) void attn_kernel(const unsigned short* __restrict__ qb,
    const unsigned short* __restrict__ kb, const unsigned short* __restrict__ vb,
    const int* __restrict__ topk_idx, const float* __restrict__ sel_w,
    const float* __restrict__ cosT, const float* __restrict__ sinT,
    unsigned short* __restrict__ oexp){
  __shared__ __align__(16) unsigned short Ks[64][136];
  __shared__ __align__(16) unsigned short Vts[128][72];
  __shared__ __align__(16) unsigned short Ps[4][16][72];
  const int qt = blockIdx.x, hh = blockIdx.y, e = blockIdx.z;
  const int tid = threadIdx.x, w = tid>>6, lane = tid&63, g = lane>>4, r16 = lane&15;
  const int* idxE = topk_idx + e*CAPN;

  // Q fragments: gathered + roped + *SCALE, held in registers for all kv tiles
  s16x8 aq[4];
  {
    int qr = qt*64 + w*16 + r16;
    int tok = idxE[qr];
    const unsigned short* qrow = qb + (size_t)tok*E_DIM + hh*DH;
    const float* cr = cosT + qr*64;
    const float* sr = sinT + qr*64;
    #pragma unroll
    for(int s=0;s<4;s++){
      int d0 = s*32 + 8*g;
      unsigned short held[8], part[8];
      *(uint4*)held = *(const uint4*)(qrow + d0);
      *(uint4*)part = *(const uint4*)(qrow + (d0^64));
      float sgn = (d0<64) ? -1.f : 1.f;
      union{ s16x8 v; unsigned short u[8]; } fr;
      #pragma unroll
      for(int jj=0;jj<8;jj++){
        int dm = (d0+jj)&63;
        float val = bf2f(held[jj])*cr[dm] + sgn*bf2f(part[jj])*sr[dm];
        fr.u[jj] = f2bf(val * SCALE_QK);
      }
      aq[s] = fr.v;
    }
  }
  float m_r[4], l_r[4];
  f32x4 o[8];
  #pragma unroll
  for(int r=0;r<4;r++){ m_r[r]=-INFINITY; l_r[r]=0.f; }
  #pragma unroll
  for(int f2=0;f2<8;f2++) o[f2]=f32x4{0.f,0.f,0.f,0.f};

  for(int kt=0; kt<=qt; kt++){
    __syncthreads();   // protect LDS from previous iteration's readers
    // stage roped K tile and transposed V tile
    for(int c=tid;c<1024;c+=256){
      int kv = c>>4, ch = c&15, d0 = ch*8;
      int rank = kt*64 + kv;
      int tok = idxE[rank];
      const unsigned short* krow = kb + (size_t)tok*E_DIM + hh*DH;
      unsigned short held[8], part[8];
      *(uint4*)held = *(const uint4*)(krow + d0);
      *(uint4*)part = *(const uint4*)(krow + (d0^64));
      const float* cr = cosT + rank*64;
      const float* sr = sinT + rank*64;
      float sgn = (d0<64) ? -1.f : 1.f;
      unsigned short outv[8];
      #pragma unroll
      for(int jj=0;jj<8;jj++){
        int dm = (d0+jj)&63;
        outv[jj] = f2bf(bf2f(held[jj])*cr[dm] + sgn*bf2f(part[jj])*sr[dm]);
      }
      *(uint4*)&Ks[kv][d0] = *(uint4*)outv;
      const unsigned short* vrow = vb + (size_t)tok*E_DIM + hh*DH;
      unsigned short vv[8];
      *(uint4*)vv = *(const uint4*)(vrow + d0);
      #pragma unroll
      for(int jj=0;jj<8;jj++) Vts[d0+jj][kv] = vv[jj];
    }
    __syncthreads();
    // S = Qr * Kr^T  (already scaled)
    f32x4 sfr[4];
    #pragma unroll
    for(int fc=0;fc<4;fc++){
      f32x4 accs = f32x4{0.f,0.f,0.f,0.f};
      #pragma unroll
      for(int s=0;s<4;s++){
        s16x8 bk = *(const s16x8*)&Ks[fc*16 + r16][s*32 + 8*g];
        accs = mfma_bf16(aq[s], bk, accs);
      }
      sfr[fc] = accs;
    }
    if (kt==qt){
      #pragma unroll
      for(int fc=0;fc<4;fc++)
        #pragma unroll
        for(int r=0;r<4;r++){
          int qrank  = qt*64 + w*16 + 4*g + r;
          int kvrank = kt*64 + fc*16 + r16;
          if (kvrank > qrank) sfr[fc][r] = NEG_BIG;
        }
    }
    // online softmax (rows live in 16-lane groups)
    float corr[4];
    #pragma unroll
    for(int r=0;r<4;r++){
      float mx = fmaxf(fmaxf(sfr[0][r],sfr[1][r]), fmaxf(sfr[2][r],sfr[3][r]));
      #pragma unroll
      for(int mk=1;mk<16;mk<<=1) mx = fmaxf(mx, __shfl_xor(mx,mk));
      float nm = fmaxf(m_r[r], mx);
      corr[r] = expf(m_r[r]-nm);
      m_r[r] = nm;
    }
    float rs[4] = {0.f,0.f,0.f,0.f};
    #pragma unroll
    for(int fc=0;fc<4;fc++)
      #pragma unroll
      for(int r=0;r<4;r++){
        float p = expf(sfr[fc][r] - m_r[r]);
        rs[r] += p;
        Ps[w][4*g+r][fc*16+r16] = f2bf(p);
      }
    #pragma unroll
    for(int r=0;r<4;r++){
      float ts = rs[r];
      #pragma unroll
      for(int mk=1;mk<16;mk<<=1) ts += __shfl_xor(ts,mk);
      l_r[r] = l_r[r]*corr[r] + ts;
    }
    #pragma unroll
    for(int f2=0;f2<8;f2++)
      #pragma unroll
      for(int r=0;r<4;r++) o[f2][r] *= corr[r];
    __syncthreads();   // Ps visible
    // O += P * V
    #pragma unroll
    for(int ks=0;ks<2;ks++){
      s16x8 pa = *(const s16x8*)&Ps[w][r16][ks*32 + 8*g];
      #pragma unroll
      for(int fd=0;fd<8;fd++){
        s16x8 vf = *(const s16x8*)&Vts[fd*16 + r16][ks*32 + 8*g];
        o[fd] = mfma_bf16(pa, vf, o[fd]);
      }
    }
  }
  // epilogue: *w/l, write per-expert output [e][rank][h*128+d]
  #pragma unroll
  for(int r=0;r<4;r++){
    int qrank = qt*64 + w*16 + 4*g + r;
    float fac = sel_w[e*CAPN + qrank] / l_r[r];
    #pragma unroll
    for(int fd=0;fd<8;fd++){
      oexp[((size_t)(e*CAPN + qrank))*E_DIM + hh*DH + fd*16 + r16] = f2bf(o[fd][r]*fac);
    }
  }
}

// ---------------- scatter-accumulate over experts ----------------
__global__ __launch_bounds__(256) void acc_kernel(const unsigned short* __restrict__ oexp,
    const int* __restrict__ rank_of, unsigned short* __restrict__ accb){
  int n = blockIdx.x, t = threadIdx.x;
  int base = t*8;
  float s[8] = {0,0,0,0,0,0,0,0};
  #pragma unroll
  for(int e=0;e<4;e++){
    int r = rank_of[e*4096+n];
    if (r>=0){
      union{uint4 q; unsigned short u[8];} ld;
      ld.q = *(const uint4*)(oexp + ((size_t)(e*CAPN+r))*E_DIM + base);
      #pragma unroll
      for(int j2=0;j2<8;j2++) s[j2] += bf2f(ld.u[j2]);
    }
  }
  union{uint4 q; unsigned short u[8];} st;
  #pragma unroll
  for(int j2=0;j2<8;j2++) st.u[j2] = f2bf(s[j2]);
  *(uint4*)(accb + (size_t)n*E_DIM + base) = st.q;
}

// ---------------- launch ----------------
extern "C" void kernel_launch(void* const* d_in, const int* in_sizes, int n_in,
                              void* d_out, int out_size, void* d_ws, size_t ws_size,
                              hipStream_t stream) {
  const float* x   = (const float*)d_in[0];
  const float* Wq  = (const float*)d_in[1];
  const float* Wk  = (const float*)d_in[2];
  const float* Wv  = (const float*)d_in[3];
  const float* Wo  = (const float*)d_in[4];
  const float* Wr1 = (const float*)d_in[5];
  const float* br1 = (const float*)d_in[6];
  const float* Wr2 = (const float*)d_in[7];
  const float* br2 = (const float*)d_in[8];

  char* ws = (char*)d_ws;
  size_t off = 0;
  auto alloc = [&](size_t bytes)->void*{
    void* p = ws + off;
    off += (bytes + 255) & ~(size_t)255;
    return p;
  };
  unsigned short* xhi   = (unsigned short*)alloc((size_t)N_TOK*E_DIM*2);
  unsigned short* xlo   = (unsigned short*)alloc((size_t)N_TOK*E_DIM*2);
  unsigned short* wr1hi = (unsigned short*)alloc((size_t)E_DIM*1024*2);   // transposed [1024][2048]
  unsigned short* wr1lo = (unsigned short*)alloc((size_t)E_DIM*1024*2);
  unsigned short* wqT   = (unsigned short*)alloc((size_t)E_DIM*E_DIM*2);
  unsigned short* wkT   = (unsigned short*)alloc((size_t)E_DIM*E_DIM*2);
  unsigned short* wvT   = (unsigned short*)alloc((size_t)E_DIM*E_DIM*2);
  unsigned short* woT   = (unsigned short*)alloc((size_t)E_DIM*E_DIM*2);
  float* hbuf   = (float*)alloc((size_t)N_TOK*1024*4);
  float* scores = (float*)alloc((size_t)N_TOK*4*4);
  float* tokmax = (float*)alloc((size_t)N_TOK*4);
  int*   topkI  = (int*)alloc((size_t)KEXP*CAPN*4);
  float* selw   = (float*)alloc((size_t)KEXP*CAPN*4);
  int*   rankof = (int*)alloc((size_t)KEXP*N_TOK*4);
  float* cosT   = (float*)alloc((size_t)CAPN*64*4);
  float* sinT   = (float*)alloc((size_t)CAPN*64*4);
  unsigned short* qbuf = (unsigned short*)alloc((size_t)N_TOK*E_DIM*2);
  unsigned short* kbuf = (unsigned short*)alloc((size_t)N_TOK*E_DIM*2);
  unsigned short* vbuf = (unsigned short*)alloc((size_t)N_TOK*E_DIM*2);
  unsigned short* oexp = (unsigned short*)alloc((size_t)KEXP*CAPN*E_DIM*2);
  unsigned short* accb = (unsigned short*)alloc((size_t)N_TOK*E_DIM*2);
  if (off > ws_size) return;   // workspace too small: fail loudly (output stays poisoned)

  // conversions
  conv_x_kernel<<<(N_TOK*E_DIM/4+255)/256, 256, 0, stream>>>(x, xhi, xlo, N_TOK*E_DIM/4);
  tconv_kernel<<<dim3(1024/32, E_DIM/32), dim3(32,8), 0, stream>>>(Wr1, wr1hi, wr1lo, E_DIM, 1024);
  tconv_kernel<<<dim3(E_DIM/32, E_DIM/32), dim3(32,8), 0, stream>>>(Wq, wqT, nullptr, E_DIM, E_DIM);
  tconv_kernel<<<dim3(E_DIM/32, E_DIM/32), dim3(32,8), 0, stream>>>(Wk, wkT, nullptr, E_DIM, E_DIM);
  tconv_kernel<<<dim3(E_DIM/32, E_DIM/32), dim3(32,8), 0, stream>>>(Wv, wvT, nullptr, E_DIM, E_DIM);
  tconv_kernel<<<dim3(E_DIM/32, E_DIM/32), dim3(32,8), 0, stream>>>(Wo, woT, nullptr, E_DIM, E_DIM);

  // router: h_pre = x@Wr1 via bf16 hi/lo split (~fp32-accurate scores for stable top-k order)
  dim3 gR(1024/128, N_TOK/128);
  gemm_kernel<0,0><<<gR, 256, 0, stream>>>(xhi, wr1hi, hbuf, 1024, E_DIM);
  gemm_kernel<1,0><<<gR, 256, 0, stream>>>(xhi, wr1lo, hbuf, 1024, E_DIM);
  gemm_kernel<1,0><<<gR, 256, 0, stream>>>(xlo, wr1hi, hbuf, 1024, E_DIM);
  gelu_kernel<<<N_TOK*1024/256, 256, 0, stream>>>(hbuf, br1);
  scores_kernel<<<N_TOK/4, 256, 0, stream>>>(hbuf, Wr2, br2, scores, tokmax);
  aux_kernel<<<1, 1024, 0, stream>>>(tokmax, ((float*)d_out) + (size_t)N_TOK*E_DIM);
  topk_kernel<<<KEXP, 1024, 0, stream>>>(scores, topkI, selw, rankof);
  rope_kernel<<<CAPN*64/256, 256, 0, stream>>>(cosT, sinT);

  // QKV projections (bf16)
  dim3 gP(E_DIM/128, N_TOK/128);
  gemm_kernel<0,1><<<gP, 256, 0, stream>>>(xhi, wqT, qbuf, E_DIM, E_DIM);
  gemm_kernel<0,1><<<gP, 256, 0, stream>>>(xhi, wkT, kbuf, E_DIM, E_DIM);
  gemm_kernel<0,1><<<gP, 256, 0, stream>>>(xhi, wvT, vbuf, E_DIM, E_DIM);

  // gathered causal attention per expert/head
  attn_kernel<<<dim3(CAPN/64, NH, KEXP), 256, 0, stream>>>(qbuf, kbuf, vbuf, topkI, selw, cosT, sinT, oexp);

  // scatter-accumulate experts -> token rows
  acc_kernel<<<N_TOK, 256, 0, stream>>>(oexp, rankof, accb);

  // final projection -> d_out
  gemm_kernel<0,0><<<gP, 256, 0, stream>>>(accb, woT, (float*)d_out, E_DIM, E_DIM);
}

// Round 2
// 688.061 us; speedup vs baseline: 1.7121x; 1.7121x over previous
//
#include <hip/hip_runtime.h>
#include <cstdint>
#include <cstddef>

// Problem constants
#define N_TOK 4096
#define E_DIM 2048
#define NH    16
#define DH    128
#define KEXP  4
#define CAPN  1280
#define SCALE_QK 0.08838834764831845f
#define NEG_BIG -1e30f

typedef __attribute__((ext_vector_type(4))) float f32x4;
typedef __attribute__((ext_vector_type(8))) short s16x8;

__device__ __forceinline__ float bf2f(unsigned short u){
  union{unsigned int i; float fl;} c; c.i = ((unsigned int)u)<<16; return c.fl;
}
__device__ __forceinline__ unsigned short f2bf(float x){
  union{float fl; unsigned int i;} c; c.fl=x;
  return (unsigned short)((c.i + 0x7FFFu + ((c.i>>16)&1u))>>16);
}
// inline-asm MFMA: avoids builtin operand-type (short8 vs bf16x8) ambiguity.
__device__ __forceinline__ f32x4 mfma_bf16(s16x8 a, s16x8 b, f32x4 c){
  asm("v_mfma_f32_16x16x32_bf16 %0, %1, %2, %0" : "+v"(c) : "v"(a), "v"(b));
  return c;
}
// async global->LDS 16B (m97 pattern): LDS dest must be linear (base + lane*16)
__device__ __forceinline__ void gl_lds16(const unsigned short* g, unsigned short* l){
  __builtin_amdgcn_global_load_lds(
      (const __attribute__((address_space(1))) unsigned int*)g,
      (__attribute__((address_space(3))) unsigned int*)l, 16, 0, 0);
}

// ---------------- conversions ----------------
__global__ __launch_bounds__(256) void conv_x_kernel(const float* __restrict__ x,
    unsigned short* __restrict__ hi, unsigned short* __restrict__ lo, int n4){
  int idx = blockIdx.x*256 + threadIdx.x;
  if (idx >= n4) return;
  float4 v = ((const float4*)x)[idx];
  float ar[4] = {v.x, v.y, v.z, v.w};
  union{ unsigned short u[4]; uint2 q; } H, L;
  #pragma unroll
  for(int i=0;i<4;i++){
    unsigned short h = f2bf(ar[i]);
    H.u[i] = h;
    L.u[i] = f2bf(ar[i] - bf2f(h));
  }
  ((uint2*)hi)[idx] = H.q;
  ((uint2*)lo)[idx] = L.q;
}

// transpose + f32->bf16 (optionally also lo residual). W[R][C] -> T[C][R]
__global__ __launch_bounds__(256) void tconv_kernel(const float* __restrict__ W,
    unsigned short* __restrict__ Thi, unsigned short* __restrict__ Tlo, int R, int C){
  __shared__ float t[32][33];
  int tx = threadIdx.x, ty = threadIdx.y;   // (32,8)
  int c0 = blockIdx.x*32, r0 = blockIdx.y*32;
  #pragma unroll
  for(int i=0;i<4;i++){
    int r = r0 + ty + i*8;
    t[ty+i*8][tx] = W[(size_t)r*C + c0 + tx];
  }
  __syncthreads();
  #pragma unroll
  for(int i=0;i<4;i++){
    int c = c0 + ty + i*8;
    float v = t[tx][ty+i*8];
    size_t o = (size_t)c*R + r0 + tx;
    unsigned short h = f2bf(v);
    Thi[o] = h;
    if (Tlo) Tlo[o] = f2bf(v - bf2f(h));
  }
}

// ---------------- bf16 MFMA GEMM (m97 structure): C[M][N] = A[M][K] * Bt[N][K]^T
template<int ACCUM, int OUTBF>
__global__ __launch_bounds__(256) void gemm_kernel(const unsigned short* __restrict__ A,
    const unsigned short* __restrict__ Bt, void* __restrict__ Cp, int N, int Kd){
  __shared__ __align__(16) unsigned short As[128][64];
  __shared__ __align__(16) unsigned short Bs[128][64];
  const int mb = blockIdx.y, nb = blockIdx.x;
  const int tid = threadIdx.x;
  const int lane = tid & 63, w = tid >> 6;
  const int g = lane >> 4, r16 = lane & 15;
  const int wm = w >> 1, wn = w & 1;
  f32x4 acc[4][4];
  #pragma unroll
  for(int i=0;i<4;i++)
    #pragma unroll
    for(int j=0;j<4;j++) acc[i][j] = f32x4{0.f,0.f,0.f,0.f};
  const unsigned short* Ab = A  + (size_t)mb*128*Kd;
  const unsigned short* Bb = Bt + (size_t)nb*128*Kd;
  const int srow = tid >> 3, sc8 = (tid & 7) * 8;   // linear LDS: byte off = tid*16
  for(int k0=0;k0<Kd;k0+=64){
    __syncthreads();   // previous iter's fragment reads done
    #pragma unroll
    for(int i=0;i<4;i++)
      gl_lds16(Ab + (size_t)(srow + i*32)*Kd + k0 + sc8, &As[srow + i*32][sc8]);
    #pragma unroll
    for(int i=0;i<4;i++)
      gl_lds16(Bb + (size_t)(srow + i*32)*Kd + k0 + sc8, &Bs[srow + i*32][sc8]);
    __syncthreads();   // compiler drains vmcnt before barrier
    #pragma unroll
    for(int ks=0;ks<2;ks++){
      s16x8 af[4], bfr[4];
      #pragma unroll
      for(int f2=0;f2<4;f2++){
        af[f2]  = *(const s16x8*)&As[wm*64 + f2*16 + r16][ks*32 + 8*g];
        bfr[f2] = *(const s16x8*)&Bs[wn*64 + f2*16 + r16][ks*32 + 8*g];
      }
      #pragma unroll
      for(int fm=0;fm<4;fm++)
        #pragma unroll
        for(int fn=0;fn<4;fn++)
          acc[fm][fn] = mfma_bf16(af[fm], bfr[fn], acc[fm][fn]);
    }
  }
  const int rowb = mb*128 + wm*64, colb = nb*128 + wn*64;
  #pragma unroll
  for(int fm=0;fm<4;fm++)
    #pragma unroll
    for(int fn=0;fn<4;fn++)
      #pragma unroll
      for(int r=0;r<4;r++){
        int rr = rowb + fm*16 + 4*g + r;
        int cc = colb + fn*16 + r16;
        size_t o = (size_t)rr*N + cc;
        float v = acc[fm][fn][r];
        if (OUTBF)        ((unsigned short*)Cp)[o] = f2bf(v);
        else if (ACCUM)   ((float*)Cp)[o] += v;
        else              ((float*)Cp)[o] = v;
      }
}

// ---------------- router pointwise ----------------
__global__ __launch_bounds__(256) void gelu_kernel(float* __restrict__ h, const float* __restrict__ br1){
  int idx = blockIdx.x*256 + threadIdx.x;   // exact 4096*1024
  float v = h[idx] + br1[idx & 1023];
  h[idx] = 0.5f*v*(1.0f + erff(v*0.70710678118654752f));
}

__global__ __launch_bounds__(256) void scores_kernel(const float* __restrict__ h,
    const float* __restrict__ Wr2, const float* __restrict__ br2,
    float* __restrict__ scores, float* __restrict__ tokmax){
  int tid = threadIdx.x;
  int n = blockIdx.x*4 + (tid>>6);
  int lane = tid & 63;
  const float* hr = h + (size_t)n*1024;
  float s0=0,s1=0,s2=0,s3=0;
  #pragma unroll
  for(int i=0;i<16;i++){
    int j = lane + i*64;
    float hv = hr[j];
    float4 wv = *(const float4*)(Wr2 + (size_t)j*4);
    s0 += hv*wv.x; s1 += hv*wv.y; s2 += hv*wv.z; s3 += hv*wv.w;
  }
  #pragma unroll
  for(int m=32;m>=1;m>>=1){
    s0 += __shfl_xor(s0,m); s1 += __shfl_xor(s1,m);
    s2 += __shfl_xor(s2,m); s3 += __shfl_xor(s3,m);
  }
  if (lane==0){
    s0+=br2[0]; s1+=br2[1]; s2+=br2[2]; s3+=br2[3];
    scores[n*4+0]=s0; scores[n*4+1]=s1; scores[n*4+2]=s2; scores[n*4+3]=s3;
    tokmax[n]=fmaxf(fmaxf(s0,s1),fmaxf(s2,s3));
  }
}

__global__ __launch_bounds__(1024) void aux_kernel(const float* __restrict__ tokmax, float* __restrict__ out_aux){
  __shared__ float red[1024];
  int t = threadIdx.x;
  red[t] = tokmax[t] + tokmax[t+1024] + tokmax[t+2048] + tokmax[t+3072];
  __syncthreads();
  for(int k=512;k>=1;k>>=1){ if(t<k) red[t]+=red[t+k]; __syncthreads(); }
  if (t==0) out_aux[0] = -red[0]/4096.0f;
}

// ---------------- exact top-k (bitonic sort of 4096 per expert) ----------------
__global__ __launch_bounds__(1024) void topk_kernel(const float* __restrict__ scores,
    int* __restrict__ topk_idx, float* __restrict__ sel_w, int* __restrict__ rank_of){
  __shared__ float sv[4096];
  __shared__ int   si[4096];
  __shared__ float red[1024];
  int e = blockIdx.x, t = threadIdx.x;
  for(int i=t;i<4096;i+=1024){ sv[i]=scores[i*4+e]; si[i]=i; }
  __syncthreads();
  for(int k=2;k<=4096;k<<=1){
    for(int j=k>>1;j>0;j>>=1){
      for(int i=t;i<4096;i+=1024){
        int ixj = i^j;
        if (ixj>i){
          float vi=sv[i], vj=sv[ixj];
          int ii=si[i], ij=si[ixj];
          bool jGreater = (vj>vi) || (vj==vi && ij<ii);
          bool asc = (i&k)==0;
          if (asc ? jGreater : !jGreater){
            sv[i]=vj; sv[ixj]=vi; si[i]=ij; si[ixj]=ii;
          }
        }
      }
      __syncthreads();
    }
  }
  for(int i=t;i<4096;i+=1024) rank_of[e*4096+i] = -1;
  __syncthreads();
  for(int r=t;r<CAPN;r+=1024){
    int tok = si[r];
    topk_idx[e*CAPN+r] = tok;
    rank_of[e*4096+tok] = r;
  }
  float mx = sv[0];
  float part = 0.f;
  for(int r=t;r<CAPN;r+=1024) part += expf(sv[r]-mx);
  red[t]=part; __syncthreads();
  for(int k=512;k>=1;k>>=1){ if(t<k) red[t]+=red[t+k]; __syncthreads(); }
  float denom = red[0];
  for(int r=t;r<CAPN;r+=1024) sel_w[e*CAPN+r] = expf(sv[r]-mx)/denom;
}

// ---------------- RoPE tables [CAPN][64] ----------------
__global__ __launch_bounds__(256) void rope_kernel(float* __restrict__ cosT, float* __restrict__ sinT){
  int idx = blockIdx.x*256 + threadIdx.x;   // exact 1280*64
  int p = idx>>6, dm = idx&63;
  float inv = powf(10000.0f, -(float)dm/64.0f);
  float ang = (float)p*inv;
  cosT[idx]=cosf(ang);
  sinT[idx]=sinf(ang);
}

// ---------------- pre-gather + pre-rope K: Kg[e][h][rank][128] ----------------
__global__ __launch_bounds__(256) void prerope_k_kernel(const unsigned short* __restrict__ kb,
    const int* __restrict__ topk_idx, const float* __restrict__ cosT, const float* __restrict__ sinT,
    unsigned short* __restrict__ Kg){
  int idx = blockIdx.x*256 + threadIdx.x;   // exact 4*16*1280*16
  int ch = idx & 15;
  int rest = idx >> 4;
  int rank = rest % CAPN;
  int he = rest / CAPN;           // e*16+h
  int e = he >> 4, h = he & 15;
  int tok = topk_idx[e*CAPN + rank];
  int d0 = ch*8;
  const unsigned short* krow = kb + (size_t)tok*E_DIM + h*DH;
  unsigned short held[8], part[8];
  *(uint4*)held = *(const uint4*)(krow + d0);
  *(uint4*)part = *(const uint4*)(krow + (d0^64));
  const float* cr = cosT + rank*64;
  const float* sr = sinT + rank*64;
  float sgn = (d0<64) ? -1.f : 1.f;
  unsigned short outv[8];
  #pragma unroll
  for(int jj=0;jj<8;jj++){
    int dm = (d0+jj)&63;
    outv[jj] = f2bf(bf2f(held[jj])*cr[dm] + sgn*bf2f(part[jj])*sr[dm]);
  }
  *(uint4*)(Kg + (size_t)idx*8) = *(uint4*)outv;
}

// ---------------- gathered causal flash attention per (qtile, head, expert) ----------------
__global__ __launch_bounds__(256) void attn_kernel(const unsigned short* __restrict__ qb,
    const unsigned short* __restrict__ Kg, const unsigned short* __restrict__ vb,
    const int* __restrict__ topk_idx, const float* __restrict__ sel_w,
    const float* __restrict__ cosT, const float* __restrict__ sinT,
    unsigned short* __restrict__ oexp){
  __shared__ __align__(16) unsigned short Ks[64][136];
  __shared__ __align__(16) unsigned short Vts[128][72];
  __shared__ __align__(16) unsigned short Ps[4][16][72];
  const int qt = gridDim.x - 1 - blockIdx.x;   // longest blocks dispatched first
  const int hh = blockIdx.y, e = blockIdx.z;
  const int tid = threadIdx.x, w = tid>>6, lane = tid&63, g = lane>>4, r16 = lane&15;
  const int* idxE = topk_idx + e*CAPN;
  const unsigned short* Kgb = Kg + (size_t)(e*NH + hh)*CAPN*DH;

  // Q fragments: gathered + roped + *SCALE, held in registers for all kv tiles
  s16x8 aq[4];
  {
    int qr = qt*64 + w*16 + r16;
    int tok = idxE[qr];
    const unsigned short* qrow = qb + (size_t)tok*E_DIM + hh*DH;
    const float* cr = cosT + qr*64;
    const float* sr = sinT + qr*64;
    #pragma unroll
    for(int s=0;s<4;s++){
      int d0 = s*32 + 8*g;
      unsigned short held[8], part[8];
      *(uint4*)held = *(const uint4*)(qrow + d0);
      *(uint4*)part = *(const uint4*)(qrow + (d0^64));
      float sgn = (d0<64) ? -1.f : 1.f;
      union{ s16x8 v; unsigned short u[8]; } fr;
      #pragma unroll
      for(int jj=0;jj<8;jj++){
        int dm = (d0+jj)&63;
        float val = bf2f(held[jj])*cr[dm] + sgn*bf2f(part[jj])*sr[dm];
        fr.u[jj] = f2bf(val * SCALE_QK);
      }
      aq[s] = fr.v;
    }
  }
  float m_r[4], l_r[4];
  f32x4 o[8];
  #pragma unroll
  for(int r=0;r<4;r++){ m_r[r]=-INFINITY; l_r[r]=0.f; }
  #pragma unroll
  for(int f2=0;f2<8;f2++) o[f2]=f32x4{0.f,0.f,0.f,0.f};

  const int kvl = tid & 63, dchb = tid >> 6;   // V staging lane remap (conflict-free writes)

  for(int kt=0; kt<=qt; kt++){
    __syncthreads();
    // K tile: pure coalesced copy of pre-roped rows
    {
      const unsigned short* Ksrc = Kgb + (size_t)(kt*64)*DH;
      #pragma unroll
      for(int i=0;i<4;i++){
        int c = tid + i*256;
        int kv = c>>4, d0 = (c&15)*8;
        *(uint4*)&Ks[kv][d0] = *(const uint4*)(Ksrc + (size_t)kv*DH + d0);
      }
    }
    // V tile: gather + transpose; kv = lane -> each store is 64 consecutive shorts (no conflicts)
    {
      int tok = idxE[kt*64 + kvl];
      const unsigned short* vrow = vb + (size_t)tok*E_DIM + hh*DH;
      #pragma unroll
      for(int i=0;i<4;i++){
        int d0 = (dchb + i*4)*8;
        unsigned short vv[8];
        *(uint4*)vv = *(const uint4*)(vrow + d0);
        #pragma unroll
        for(int jj=0;jj<8;jj++) Vts[d0+jj][kvl] = vv[jj];
      }
    }
    __syncthreads();
    // S = Qr * Kr^T  (already scaled)
    f32x4 sfr[4];
    #pragma unroll
    for(int fc=0;fc<4;fc++){
      f32x4 accs = f32x4{0.f,0.f,0.f,0.f};
      #pragma unroll
      for(int s=0;s<4;s++){
        s16x8 bk = *(const s16x8*)&Ks[fc*16 + r16][s*32 + 8*g];
        accs = mfma_bf16(aq[s], bk, accs);
      }
      sfr[fc] = accs;
    }
    if (kt==qt){
      #pragma unroll
      for(int fc=0;fc<4;fc++)
        #pragma unroll
        for(int r=0;r<4;r++){
          int qrank  = qt*64 + w*16 + 4*g + r;
          int kvrank = kt*64 + fc*16 + r16;
          if (kvrank > qrank) sfr[fc][r] = NEG_BIG;
        }
    }
    // online softmax (rows live in 16-lane groups)
    float corr[4];
    #pragma unroll
    for(int r=0;r<4;r++){
      float mx = fmaxf(fmaxf(sfr[0][r],sfr[1][r]), fmaxf(sfr[2][r],sfr[3][r]));
      #pragma unroll
      for(int mk=1;mk<16;mk<<=1) mx = fmaxf(mx, __shfl_xor(mx,mk));
      float nm = fmaxf(m_r[r], mx);
      corr[r] = expf(m_r[r]-nm);
      m_r[r] = nm;
    }
    float rs[4] = {0.f,0.f,0.f,0.f};
    #pragma unroll
    for(int fc=0;fc<4;fc++)
      #pragma unroll
      for(int r=0;r<4;r++){
        float p = expf(sfr[fc][r] - m_r[r]);
        rs[r] += p;
        Ps[w][4*g+r][fc*16+r16] = f2bf(p);
      }
    #pragma unroll
    for(int r=0;r<4;r++){
      float ts = rs[r];
      #pragma unroll
      for(int mk=1;mk<16;mk<<=1) ts += __shfl_xor(ts,mk);
      l_r[r] = l_r[r]*corr[r] + ts;
    }
    #pragma unroll
    for(int f2=0;f2<8;f2++)
      #pragma unroll
      for(int r=0;r<4;r++) o[f2][r] *= corr[r];
    __syncthreads();   // Ps + Vts visible
    // O += P * V
    #pragma unroll
    for(int ks=0;ks<2;ks++){
      s16x8 pa = *(const s16x8*)&Ps[w][r16][ks*32 + 8*g];
      #pragma unroll
      for(int fd=0;fd<8;fd++){
        s16x8 vf = *(const s16x8*)&Vts[fd*16 + r16][ks*32 + 8*g];
        o[fd] = mfma_bf16(pa, vf, o[fd]);
      }
    }
  }
  // epilogue: *w/l, write per-expert output [e][rank][h*128+d]
  #pragma unroll
  for(int r=0;r<4;r++){
    int qrank = qt*64 + w*16 + 4*g + r;
    float fac = sel_w[e*CAPN + qrank] / l_r[r];
    #pragma unroll
    for(int fd=0;fd<8;fd++){
      oexp[((size_t)(e*CAPN + qrank))*E_DIM + hh*DH + fd*16 + r16] = f2bf(o[fd][r]*fac);
    }
  }
}

// ---------------- scatter-accumulate over experts ----------------
__global__ __launch_bounds__(256) void acc_kernel(const unsigned short* __restrict__ oexp,
    const int* __restrict__ rank_of, unsigned short* __restrict__ accb){
  int n = blockIdx.x, t = threadIdx.x;
  int base = t*8;
  float s[8] = {0,0,0,0,0,0,0,0};
  #pragma unroll
  for(int e=0;e<4;e++){
    int r = rank_of[e*4096+n];
    if (r>=0){
      union{uint4 q; unsigned short u[8];} ld;
      ld.q = *(const uint4*)(oexp + ((size_t)(e*CAPN+r))*E_DIM + base);
      #pragma unroll
      for(int j2=0;j2<8;j2++) s[j2] += bf2f(ld.u[j2]);
    }
  }
  union{uint4 q; unsigned short u[8];} st;
  #pragma unroll
  for(int j2=0;j2<8;j2++) st.u[j2] = f2bf(s[j2]);
  *(uint4*)(accb + (size_t)n*E_DIM + base) = st.q;
}

// ---------------- launch ----------------
extern "C" void kernel_launch(void* const* d_in, const int* in_sizes, int n_in,
                              void* d_out, int out_size, void* d_ws, size_t ws_size,
                              hipStream_t stream) {
  const float* x   = (const float*)d_in[0];
  const float* Wq  = (const float*)d_in[1];
  const float* Wk  = (const float*)d_in[2];
  const float* Wv  = (const float*)d_in[3];
  const float* Wo  = (const float*)d_in[4];
  const float* Wr1 = (const float*)d_in[5];
  const float* br1 = (const float*)d_in[6];
  const float* Wr2 = (const float*)d_in[7];
  const float* br2 = (const float*)d_in[8];

  char* ws = (char*)d_ws;
  size_t off = 0;
  auto alloc = [&](size_t bytes)->void*{
    void* p = ws + off;
    off += (bytes + 255) & ~(size_t)255;
    return p;
  };
  unsigned short* xhi   = (unsigned short*)alloc((size_t)N_TOK*E_DIM*2);
  unsigned short* xlo   = (unsigned short*)alloc((size_t)N_TOK*E_DIM*2);
  unsigned short* wr1hi = (unsigned short*)alloc((size_t)E_DIM*1024*2);   // transposed [1024][2048]
  unsigned short* wr1lo = (unsigned short*)alloc((size_t)E_DIM*1024*2);
  unsigned short* wqT   = (unsigned short*)alloc((size_t)E_DIM*E_DIM*2);
  unsigned short* wkT   = (unsigned short*)alloc((size_t)E_DIM*E_DIM*2);
  unsigned short* wvT   = (unsigned short*)alloc((size_t)E_DIM*E_DIM*2);
  unsigned short* woT   = (unsigned short*)alloc((size_t)E_DIM*E_DIM*2);
  float* hbuf   = (float*)alloc((size_t)N_TOK*1024*4);
  float* scores = (float*)alloc((size_t)N_TOK*4*4);
  float* tokmax = (float*)alloc((size_t)N_TOK*4);
  int*   topkI  = (int*)alloc((size_t)KEXP*CAPN*4);
  float* selw   = (float*)alloc((size_t)KEXP*CAPN*4);
  int*   rankof = (int*)alloc((size_t)KEXP*N_TOK*4);
  float* cosT   = (float*)alloc((size_t)CAPN*64*4);
  float* sinT   = (float*)alloc((size_t)CAPN*64*4);
  unsigned short* qbuf = (unsigned short*)alloc((size_t)N_TOK*E_DIM*2);
  unsigned short* kbuf = (unsigned short*)alloc((size_t)N_TOK*E_DIM*2);
  unsigned short* vbuf = (unsigned short*)alloc((size_t)N_TOK*E_DIM*2);
  unsigned short* oexp = (unsigned short*)alloc((size_t)KEXP*CAPN*E_DIM*2);
  unsigned short* accb = (unsigned short*)alloc((size_t)N_TOK*E_DIM*2);
  if (off > ws_size) return;   // workspace too small: fail loudly (output stays poisoned)

  // Kg[e][h][rank][128] (21.0 MB) aliases xlo+wr1hi+wr1lo (25.2 MB), which are
  // dead after the router GEMMs; prerope_k runs strictly later.
  unsigned short* Kg = xlo;

  // conversions
  conv_x_kernel<<<(N_TOK*E_DIM/4+255)/256, 256, 0, stream>>>(x, xhi, xlo, N_TOK*E_DIM/4);
  tconv_kernel<<<dim3(1024/32, E_DIM/32), dim3(32,8), 0, stream>>>(Wr1, wr1hi, wr1lo, E_DIM, 1024);
  tconv_kernel<<<dim3(E_DIM/32, E_DIM/32), dim3(32,8), 0, stream>>>(Wq, wqT, nullptr, E_DIM, E_DIM);
  tconv_kernel<<<dim3(E_DIM/32, E_DIM/32), dim3(32,8), 0, stream>>>(Wk, wkT, nullptr, E_DIM, E_DIM);
  tconv_kernel<<<dim3(E_DIM/32, E_DIM/32), dim3(32,8), 0, stream>>>(Wv, wvT, nullptr, E_DIM, E_DIM);
  tconv_kernel<<<dim3(E_DIM/32, E_DIM/32), dim3(32,8), 0, stream>>>(Wo, woT, nullptr, E_DIM, E_DIM);

  // router: h_pre = x@Wr1 via bf16 hi/lo split (~fp32-accurate scores for stable top-k order)
  dim3 gR(1024/128, N_TOK/128);
  gemm_kernel<0,0><<<gR, 256, 0, stream>>>(xhi, wr1hi, hbuf, 1024, E_DIM);
  gemm_kernel<1,0><<<gR, 256, 0, stream>>>(xhi, wr1lo, hbuf, 1024, E_DIM);
  gemm_kernel<1,0><<<gR, 256, 0, stream>>>(xlo, wr1hi, hbuf, 1024, E_DIM);
  gelu_kernel<<<N_TOK*1024/256, 256, 0, stream>>>(hbuf, br1);
  scores_kernel<<<N_TOK/4, 256, 0, stream>>>(hbuf, Wr2, br2, scores, tokmax);
  aux_kernel<<<1, 1024, 0, stream>>>(tokmax, ((float*)d_out) + (size_t)N_TOK*E_DIM);
  topk_kernel<<<KEXP, 1024, 0, stream>>>(scores, topkI, selw, rankof);
  rope_kernel<<<CAPN*64/256, 256, 0, stream>>>(cosT, sinT);

  // QKV projections (bf16)
  dim3 gP(E_DIM/128, N_TOK/128);
  gemm_kernel<0,1><<<gP, 256, 0, stream>>>(xhi, wqT, qbuf, E_DIM, E_DIM);
  gemm_kernel<0,1><<<gP, 256, 0, stream>>>(xhi, wkT, kbuf, E_DIM, E_DIM);
  gemm_kernel<0,1><<<gP, 256, 0, stream>>>(xhi, wvT, vbuf, E_DIM, E_DIM);

  // pre-gather + pre-rope K into dense per-(e,h) layout
  prerope_k_kernel<<<KEXP*NH*CAPN*16/256, 256, 0, stream>>>(kbuf, topkI, cosT, sinT, Kg);

  // gathered causal attention per expert/head
  attn_kernel<<<dim3(CAPN/64, NH, KEXP), 256, 0, stream>>>(qbuf, Kg, vbuf, topkI, selw, cosT, sinT, oexp);

  // scatter-accumulate experts -> token rows
  acc_kernel<<<N_TOK, 256, 0, stream>>>(oexp, rankof, accb);

  // final projection -> d_out
  gemm_kernel<0,0><<<gP, 256, 0, stream>>>(accb, woT, (float*)d_out, E_DIM, E_DIM);
}

// Round 3
// 510.493 us; speedup vs baseline: 2.3077x; 1.3478x over previous
//
#include <hip/hip_runtime.h>
#include <cstdint>
#include <cstddef>

// Problem constants
#define N_TOK 4096
#define E_DIM 2048
#define NH    16
#define DH    128
#define KEXP  4
#define CAPN  1280
#define NTILE 20                 // CAPN/64
#define QKV_STRIDE 6144          // fused QKV output row stride
#define SCALE_QK 0.08838834764831845f
#define LOG2E    1.4426950408889634f
#define NEG_BIG -1e30f

typedef __attribute__((ext_vector_type(4))) float f32x4;
typedef __attribute__((ext_vector_type(8))) short s16x8;

__device__ __forceinline__ float bf2f(unsigned short u){
  union{unsigned int i; float fl;} c; c.i = ((unsigned int)u)<<16; return c.fl;
}
__device__ __forceinline__ unsigned short f2bf(float x){
  union{float fl; unsigned int i;} c; c.fl=x;
  return (unsigned short)((c.i + 0x7FFFu + ((c.i>>16)&1u))>>16);
}
__device__ __forceinline__ f32x4 mfma_bf16(s16x8 a, s16x8 b, f32x4 c){
  asm("v_mfma_f32_16x16x32_bf16 %0, %1, %2, %0" : "+v"(c) : "v"(a), "v"(b));
  return c;
}
// async global->LDS 16B: LDS dest must be lane-linear (base + lane*16)
__device__ __forceinline__ void gl_lds16(const unsigned short* g, unsigned short* l){
  __builtin_amdgcn_global_load_lds(
      (const __attribute__((address_space(1))) unsigned int*)g,
      (__attribute__((address_space(3))) unsigned int*)l, 16, 0, 0);
}

// ---------------- conversions ----------------
__global__ __launch_bounds__(256) void conv_x_kernel(const float* __restrict__ x,
    unsigned short* __restrict__ hi, unsigned short* __restrict__ lo, int n4){
  int idx = blockIdx.x*256 + threadIdx.x;
  if (idx >= n4) return;
  float4 v = ((const float4*)x)[idx];
  float ar[4] = {v.x, v.y, v.z, v.w};
  union{ unsigned short u[4]; uint2 q; } H, L;
  #pragma unroll
  for(int i=0;i<4;i++){
    unsigned short h = f2bf(ar[i]);
    H.u[i] = h;
    L.u[i] = f2bf(ar[i] - bf2f(h));
  }
  ((uint2*)hi)[idx] = H.q;
  ((uint2*)lo)[idx] = L.q;
}

// transpose + f32->bf16 (optionally also lo residual). W[R][C] -> T[C][R]
__global__ __launch_bounds__(256) void tconv_kernel(const float* __restrict__ W,
    unsigned short* __restrict__ Thi, unsigned short* __restrict__ Tlo, int R, int C){
  __shared__ float t[32][33];
  int tx = threadIdx.x, ty = threadIdx.y;   // (32,8)
  int c0 = blockIdx.x*32, r0 = blockIdx.y*32;
  #pragma unroll
  for(int i=0;i<4;i++){
    int r = r0 + ty + i*8;
    t[ty+i*8][tx] = W[(size_t)r*C + c0 + tx];
  }
  __syncthreads();
  #pragma unroll
  for(int i=0;i<4;i++){
    int c = c0 + ty + i*8;
    float v = t[tx][ty+i*8];
    size_t o = (size_t)c*R + r0 + tx;
    unsigned short h = f2bf(v);
    Thi[o] = h;
    if (Tlo) Tlo[o] = f2bf(v - bf2f(h));
  }
}

// ---------------- bf16 MFMA GEMM (m97 structure): C[M][N] = A[M][K] * Bt[N][K]^T
template<int ACCUM, int OUTBF>
__global__ __launch_bounds__(256) void gemm_kernel(const unsigned short* __restrict__ A,
    const unsigned short* __restrict__ Bt, void* __restrict__ Cp, int N, int Kd){
  __shared__ __align__(16) unsigned short As[128][64];
  __shared__ __align__(16) unsigned short Bs[128][64];
  const int mb = blockIdx.y, nb = blockIdx.x;
  const int tid = threadIdx.x;
  const int lane = tid & 63, w = tid >> 6;
  const int g = lane >> 4, r16 = lane & 15;
  const int wm = w >> 1, wn = w & 1;
  f32x4 acc[4][4];
  #pragma unroll
  for(int i=0;i<4;i++)
    #pragma unroll
    for(int j=0;j<4;j++) acc[i][j] = f32x4{0.f,0.f,0.f,0.f};
  const unsigned short* Ab = A  + (size_t)mb*128*Kd;
  const unsigned short* Bb = Bt + (size_t)nb*128*Kd;
  const int srow = tid >> 3, sc8 = (tid & 7) * 8;   // linear LDS: byte off = tid*16
  for(int k0=0;k0<Kd;k0+=64){
    __syncthreads();
    #pragma unroll
    for(int i=0;i<4;i++)
      gl_lds16(Ab + (size_t)(srow + i*32)*Kd + k0 + sc8, &As[srow + i*32][sc8]);
    #pragma unroll
    for(int i=0;i<4;i++)
      gl_lds16(Bb + (size_t)(srow + i*32)*Kd + k0 + sc8, &Bs[srow + i*32][sc8]);
    __syncthreads();
    #pragma unroll
    for(int ks=0;ks<2;ks++){
      s16x8 af[4], bfr[4];
      #pragma unroll
      for(int f2=0;f2<4;f2++){
        af[f2]  = *(const s16x8*)&As[wm*64 + f2*16 + r16][ks*32 + 8*g];
        bfr[f2] = *(const s16x8*)&Bs[wn*64 + f2*16 + r16][ks*32 + 8*g];
      }
      #pragma unroll
      for(int fm=0;fm<4;fm++)
        #pragma unroll
        for(int fn=0;fn<4;fn++)
          acc[fm][fn] = mfma_bf16(af[fm], bfr[fn], acc[fm][fn]);
    }
  }
  const int rowb = mb*128 + wm*64, colb = nb*128 + wn*64;
  #pragma unroll
  for(int fm=0;fm<4;fm++)
    #pragma unroll
    for(int fn=0;fn<4;fn++)
      #pragma unroll
      for(int r=0;r<4;r++){
        int rr = rowb + fm*16 + 4*g + r;
        int cc = colb + fn*16 + r16;
        size_t o = (size_t)rr*N + cc;
        float v = acc[fm][fn][r];
        if (OUTBF)        ((unsigned short*)Cp)[o] = f2bf(v);
        else if (ACCUM)   ((float*)Cp)[o] += v;
        else              ((float*)Cp)[o] = v;
      }
}

// ---------------- fused router GEMM: H = gelu(x@Wr1 + br1) via hi/lo split ----------------
// acc += Ahi*Bhi + Ahi*Blo + Alo*Bhi   (BK=32, 32KB LDS)
__global__ __launch_bounds__(256) void gemm_router_kernel(
    const unsigned short* __restrict__ Ahi, const unsigned short* __restrict__ Alo,
    const unsigned short* __restrict__ Bhi, const unsigned short* __restrict__ Blo,
    const float* __restrict__ br1, float* __restrict__ H){
  __shared__ __align__(16) unsigned short AsH[128*32];
  __shared__ __align__(16) unsigned short AsL[128*32];
  __shared__ __align__(16) unsigned short BsH[128*32];
  __shared__ __align__(16) unsigned short BsL[128*32];
  const int mb = blockIdx.y, nb = blockIdx.x;
  const int tid = threadIdx.x;
  const int lane = tid & 63, w = tid >> 6;
  const int g = lane >> 4, r16 = lane & 15;
  const int wm = w >> 1, wn = w & 1;
  f32x4 acc[4][4];
  #pragma unroll
  for(int i=0;i<4;i++)
    #pragma unroll
    for(int j=0;j<4;j++) acc[i][j] = f32x4{0.f,0.f,0.f,0.f};
  const unsigned short* AbH = Ahi + (size_t)mb*128*E_DIM;
  const unsigned short* AbL = Alo + (size_t)mb*128*E_DIM;
  const unsigned short* BbH = Bhi + (size_t)nb*128*E_DIM;
  const unsigned short* BbL = Blo + (size_t)nb*128*E_DIM;
  for(int k0=0;k0<E_DIM;k0+=32){
    __syncthreads();
    #pragma unroll
    for(int i=0;i<2;i++){
      int c = i*256 + tid;
      int row = c>>2, sc = (c&3)*8;
      size_t go = (size_t)row*E_DIM + k0 + sc;
      gl_lds16(AbH + go, &AsH[c*8]);
      gl_lds16(AbL + go, &AsL[c*8]);
      gl_lds16(BbH + go, &BsH[c*8]);
      gl_lds16(BbL + go, &BsL[c*8]);
    }
    __syncthreads();
    s16x8 ah[4], al[4], bh[4], bl[4];
    #pragma unroll
    for(int f2=0;f2<4;f2++){
      int ra = (wm*64 + f2*16 + r16)*32 + 8*g;
      int rb = (wn*64 + f2*16 + r16)*32 + 8*g;
      ah[f2] = *(const s16x8*)&AsH[ra];
      al[f2] = *(const s16x8*)&AsL[ra];
      bh[f2] = *(const s16x8*)&BsH[rb];
      bl[f2] = *(const s16x8*)&BsL[rb];
    }
    #pragma unroll
    for(int fm=0;fm<4;fm++)
      #pragma unroll
      for(int fn=0;fn<4;fn++){
        acc[fm][fn] = mfma_bf16(ah[fm], bh[fn], acc[fm][fn]);
        acc[fm][fn] = mfma_bf16(ah[fm], bl[fn], acc[fm][fn]);
        acc[fm][fn] = mfma_bf16(al[fm], bh[fn], acc[fm][fn]);
      }
  }
  const int rowb = mb*128 + wm*64, colb = nb*128 + wn*64;
  #pragma unroll
  for(int fm=0;fm<4;fm++)
    #pragma unroll
    for(int fn=0;fn<4;fn++)
      #pragma unroll
      for(int r=0;r<4;r++){
        int rr = rowb + fm*16 + 4*g + r;
        int cc = colb + fn*16 + r16;
        float v = acc[fm][fn][r] + br1[cc];
        H[(size_t)rr*1024 + cc] = 0.5f*v*(1.0f + erff(v*0.70710678118654752f));
      }
}

// ---------------- router scores ----------------
__global__ __launch_bounds__(256) void scores_kernel(const float* __restrict__ h,
    const float* __restrict__ Wr2, const float* __restrict__ br2,
    float* __restrict__ scores, float* __restrict__ tokmax){
  int tid = threadIdx.x;
  int n = blockIdx.x*4 + (tid>>6);
  int lane = tid & 63;
  const float* hr = h + (size_t)n*1024;
  float s0=0,s1=0,s2=0,s3=0;
  #pragma unroll
  for(int i=0;i<16;i++){
    int j = lane + i*64;
    float hv = hr[j];
    float4 wv = *(const float4*)(Wr2 + (size_t)j*4);
    s0 += hv*wv.x; s1 += hv*wv.y; s2 += hv*wv.z; s3 += hv*wv.w;
  }
  #pragma unroll
  for(int m=32;m>=1;m>>=1){
    s0 += __shfl_xor(s0,m); s1 += __shfl_xor(s1,m);
    s2 += __shfl_xor(s2,m); s3 += __shfl_xor(s3,m);
  }
  if (lane==0){
    s0+=br2[0]; s1+=br2[1]; s2+=br2[2]; s3+=br2[3];
    scores[n*4+0]=s0; scores[n*4+1]=s1; scores[n*4+2]=s2; scores[n*4+3]=s3;
    tokmax[n]=fmaxf(fmaxf(s0,s1),fmaxf(s2,s3));
  }
}

__global__ __launch_bounds__(1024) void aux_kernel(const float* __restrict__ tokmax, float* __restrict__ out_aux){
  __shared__ float red[1024];
  int t = threadIdx.x;
  red[t] = tokmax[t] + tokmax[t+1024] + tokmax[t+2048] + tokmax[t+3072];
  __syncthreads();
  for(int k=512;k>=1;k>>=1){ if(t<k) red[t]+=red[t+k]; __syncthreads(); }
  if (t==0) out_aux[0] = -red[0]/4096.0f;
}

// ---------------- exact top-k (bitonic sort of 4096 per expert) ----------------
__global__ __launch_bounds__(1024) void topk_kernel(const float* __restrict__ scores,
    int* __restrict__ topk_idx, float* __restrict__ sel_w, int* __restrict__ rank_of){
  __shared__ float sv[4096];
  __shared__ int   si[4096];
  __shared__ float red[1024];
  int e = blockIdx.x, t = threadIdx.x;
  for(int i=t;i<4096;i+=1024){ sv[i]=scores[i*4+e]; si[i]=i; }
  __syncthreads();
  for(int k=2;k<=4096;k<<=1){
    for(int j=k>>1;j>0;j>>=1){
      for(int i=t;i<4096;i+=1024){
        int ixj = i^j;
        if (ixj>i){
          float vi=sv[i], vj=sv[ixj];
          int ii=si[i], ij=si[ixj];
          bool jGreater = (vj>vi) || (vj==vi && ij<ii);
          bool asc = (i&k)==0;
          if (asc ? jGreater : !jGreater){
            sv[i]=vj; sv[ixj]=vi; si[i]=ij; si[ixj]=ii;
          }
        }
      }
      __syncthreads();
    }
  }
  for(int i=t;i<4096;i+=1024) rank_of[e*4096+i] = -1;
  __syncthreads();
  for(int r=t;r<CAPN;r+=1024){
    int tok = si[r];
    topk_idx[e*CAPN+r] = tok;
    rank_of[e*4096+tok] = r;
  }
  float mx = sv[0];
  float part = 0.f;
  for(int r=t;r<CAPN;r+=1024) part += expf(sv[r]-mx);
  red[t]=part; __syncthreads();
  for(int k=512;k>=1;k>>=1){ if(t<k) red[t]+=red[t+k]; __syncthreads(); }
  float denom = red[0];
  for(int r=t;r<CAPN;r+=1024) sel_w[e*CAPN+r] = expf(sv[r]-mx)/denom;
}

// ---------------- RoPE tables [CAPN][64] ----------------
__global__ __launch_bounds__(256) void rope_kernel(float* __restrict__ cosT, float* __restrict__ sinT){
  int idx = blockIdx.x*256 + threadIdx.x;
  int p = idx>>6, dm = idx&63;
  float inv = powf(10000.0f, -(float)dm/64.0f);
  float ang = (float)p*inv;
  cosT[idx]=cosf(ang);
  sinT[idx]=sinf(ang);
}

// ---------------- pre-gather + pre-rope K into swizzled tiles ----------------
// Kg layout: [(e*16+h)*20 + t] tiles of 64x128 bf16; within a row, 16B chunk ch
// stored at position ch ^ (row&7)  (XOR swizzle baked into global layout)
__global__ __launch_bounds__(256) void prerope_k_kernel(const unsigned short* __restrict__ kb,
    const int* __restrict__ topk_idx, const float* __restrict__ cosT, const float* __restrict__ sinT,
    unsigned short* __restrict__ Kg){
  int idx = blockIdx.x*256 + threadIdx.x;   // exact 4*16*1280*16
  int ch = idx & 15;
  int rest = idx >> 4;
  int rank = rest % CAPN;
  int he = rest / CAPN;           // e*16+h
  int e = he >> 4, h = he & 15;
  int tok = topk_idx[e*CAPN + rank];
  int d0 = ch*8;
  const unsigned short* krow = kb + (size_t)tok*QKV_STRIDE + h*DH;
  unsigned short held[8], part[8];
  *(uint4*)held = *(const uint4*)(krow + d0);
  *(uint4*)part = *(const uint4*)(krow + (d0^64));
  const float* cr = cosT + rank*64;
  const float* sr = sinT + rank*64;
  float sgn = (d0<64) ? -1.f : 1.f;
  unsigned short outv[8];
  #pragma unroll
  for(int jj=0;jj<8;jj++){
    int dm = (d0+jj)&63;
    outv[jj] = f2bf(bf2f(held[jj])*cr[dm] + sgn*bf2f(part[jj])*sr[dm]);
  }
  int t = rank >> 6, row = rank & 63;
  size_t tbase = ((size_t)(he)*NTILE + t) * 8192;
  *(uint4*)(Kg + tbase + row*128 + ((ch ^ (row&7))<<3)) = *(uint4*)outv;
}

// ---------------- pre-gather + transpose V into swizzled tiles ----------------
// Vg layout: tiles of 128(d) x 64(rank) bf16; within a 128B d-row, 16B chunk ch
// stored at ch ^ (d&7)
__global__ __launch_bounds__(256) void prev_kernel(const unsigned short* __restrict__ vb,
    const int* __restrict__ topk_idx, unsigned short* __restrict__ Vg){
  __shared__ __align__(16) unsigned short T2[128][72];
  int bid = blockIdx.x;           // e*320 + h*20 + t
  int t = bid % NTILE, h = (bid/NTILE) & 15, e = bid/(NTILE*NH);
  int tid = threadIdx.x, lane = tid & 63, dchb = tid >> 6;
  int tok = topk_idx[e*CAPN + t*64 + lane];
  const unsigned short* vrow = vb + (size_t)tok*QKV_STRIDE + h*DH;
  #pragma unroll
  for(int i=0;i<4;i++){
    int d0 = (dchb + i*4)*8;
    unsigned short vv[8];
    *(uint4*)vv = *(const uint4*)(vrow + d0);
    #pragma unroll
    for(int j=0;j<8;j++) T2[d0+j][lane] = vv[j];   // lane-consecutive: conflict-free
  }
  __syncthreads();
  unsigned short* out = Vg + ((size_t)(e*NH+h)*NTILE + t)*8192;
  #pragma unroll
  for(int i=0;i<4;i++){
    int c = i*256 + tid;
    int d = c>>3, ch = c&7;
    *(uint4*)(out + d*64 + ((ch ^ (d&7))<<3)) = *(const uint4*)&T2[d][ch*8];
  }
}

// ---------------- gathered causal flash attention ----------------
// grid: 1280 1D, XCD-swizzled; per block: 64 Q rows, loop kv tiles
__global__ __launch_bounds__(256) void attn_kernel(
    const unsigned short* __restrict__ qb,
    const unsigned short* __restrict__ Kg, const unsigned short* __restrict__ Vg,
    const int* __restrict__ topk_idx, const float* __restrict__ sel_w,
    const float* __restrict__ cosT, const float* __restrict__ sinT,
    unsigned short* __restrict__ oexp){
  __shared__ __align__(16) unsigned short KsA[2][8192];
  __shared__ __align__(16) unsigned short Vs[8192];
  __shared__ __align__(16) unsigned short Ps[4][16][72];
  // XCD-aware decode: blocks of one (e,h) group stay on one XCD
  const int id = blockIdx.x;
  const int xcd = id & 7, s_ = id >> 3;
  const int qt = NTILE - 1 - (s_ % NTILE);          // longest first
  const int grp = (s_ / NTILE)*8 + xcd;             // 0..63
  const int e = grp >> 4, hh = grp & 15;
  const int tid = threadIdx.x, w = tid>>6, lane = tid&63, g = lane>>4, r16 = lane&15;
  const int* idxE = topk_idx + e*CAPN;
  const unsigned short* Kgb = Kg + (size_t)(e*NH+hh)*CAPN*DH;
  const unsigned short* Vgb = Vg + (size_t)(e*NH+hh)*CAPN*DH;

  // Q fragments: gathered + roped + *(SCALE*LOG2E), in registers for all kv tiles
  s16x8 aq[4];
  {
    int qr = qt*64 + w*16 + r16;
    int tok = idxE[qr];
    const unsigned short* qrow = qb + (size_t)tok*QKV_STRIDE + hh*DH;
    const float* cr = cosT + qr*64;
    const float* sr = sinT + qr*64;
    #pragma unroll
    for(int s=0;s<4;s++){
      int d0 = s*32 + 8*g;
      unsigned short held[8], part[8];
      *(uint4*)held = *(const uint4*)(qrow + d0);
      *(uint4*)part = *(const uint4*)(qrow + (d0^64));
      float sgn = (d0<64) ? -1.f : 1.f;
      union{ s16x8 v; unsigned short u[8]; } fr;
      #pragma unroll
      for(int jj=0;jj<8;jj++){
        int dm = (d0+jj)&63;
        float val = bf2f(held[jj])*cr[dm] + sgn*bf2f(part[jj])*sr[dm];
        fr.u[jj] = f2bf(val * (SCALE_QK*LOG2E));
      }
      aq[s] = fr.v;
    }
  }
  float m_r[4], l_r[4];
  f32x4 o[8];
  #pragma unroll
  for(int r=0;r<4;r++){ m_r[r]=-INFINITY; l_r[r]=0.f; }
  #pragma unroll
  for(int f2=0;f2<8;f2++) o[f2]=f32x4{0.f,0.f,0.f,0.f};

  // prologue stage (tile 0): K into buf0, V into Vs
  #pragma unroll
  for(int i=0;i<4;i++){ int c=i*256+tid; gl_lds16(Kgb + c*8, &KsA[0][c*8]); }
  #pragma unroll
  for(int i=0;i<4;i++){ int c=i*256+tid; gl_lds16(Vgb + c*8, &Vs[c*8]); }
  __syncthreads();

  for(int kt=0; kt<=qt; kt++){
    const int cur = kt & 1;
    // prefetch next K tile (hidden under QK^T + softmax)
    if (kt < qt){
      const unsigned short* Ksrc = Kgb + (size_t)(kt+1)*8192;
      #pragma unroll
      for(int i=0;i<4;i++){ int c=i*256+tid; gl_lds16(Ksrc + c*8, &KsA[cur^1][c*8]); }
    }
    // S = Qr * Kr^T (log2-domain, already scaled)
    f32x4 sfr[4];
    #pragma unroll
    for(int fc=0;fc<4;fc++){
      f32x4 a4 = f32x4{0.f,0.f,0.f,0.f};
      const int row = fc*16 + r16;
      #pragma unroll
      for(int s=0;s<4;s++){
        s16x8 bk = *(const s16x8*)&KsA[cur][row*128 + (((s*4+g) ^ (r16&7))<<3)];
        a4 = mfma_bf16(aq[s], bk, a4);
      }
      sfr[fc] = a4;
    }
    if (kt==qt){
      #pragma unroll
      for(int fc=0;fc<4;fc++)
        #pragma unroll
        for(int r=0;r<4;r++){
          int qrank  = qt*64 + w*16 + 4*g + r;
          int kvrank = kt*64 + fc*16 + r16;
          if (kvrank > qrank) sfr[fc][r] = NEG_BIG;
        }
    }
    // online softmax (exp2 domain); rows in 16-lane groups
    float corr[4];
    bool need = false;
    #pragma unroll
    for(int r=0;r<4;r++){
      float mx = fmaxf(fmaxf(sfr[0][r],sfr[1][r]), fmaxf(sfr[2][r],sfr[3][r]));
      #pragma unroll
      for(int mk=1;mk<16;mk<<=1) mx = fmaxf(mx, __shfl_xor(mx,mk));
      float nm = fmaxf(m_r[r], mx);
      need = need || (nm > m_r[r]);
      corr[r] = exp2f(m_r[r]-nm);
      m_r[r] = nm;
    }
    if (__any(need)){
      #pragma unroll
      for(int f2=0;f2<8;f2++)
        #pragma unroll
        for(int r=0;r<4;r++) o[f2][r] *= corr[r];
      #pragma unroll
      for(int r=0;r<4;r++) l_r[r] *= corr[r];
    }
    float rs[4] = {0.f,0.f,0.f,0.f};
    #pragma unroll
    for(int fc=0;fc<4;fc++)
      #pragma unroll
      for(int r=0;r<4;r++){
        float p = exp2f(sfr[fc][r] - m_r[r]);
        rs[r] += p;
        Ps[w][4*g+r][fc*16+r16] = f2bf(p);
      }
    #pragma unroll
    for(int r=0;r<4;r++){
      float ts = rs[r];
      #pragma unroll
      for(int mk=1;mk<16;mk<<=1) ts += __shfl_xor(ts,mk);
      l_r[r] += ts;
    }
    __syncthreads();   // Ps visible; V(kt) staged; K(kt+1) also drained
    // O += P * V
    #pragma unroll
    for(int ks=0;ks<2;ks++){
      s16x8 pa = *(const s16x8*)&Ps[w][r16][ks*32 + 8*g];
      #pragma unroll
      for(int fd=0;fd<8;fd++){
        const int row = fd*16 + r16;
        s16x8 vf = *(const s16x8*)&Vs[row*64 + (((ks*4+g) ^ (r16&7))<<3)];
        o[fd] = mfma_bf16(pa, vf, o[fd]);
      }
    }
    __syncthreads();   // PV reads of Vs/Ps done
    // stage next V tile (hidden under next QK^T + softmax)
    if (kt < qt){
      const unsigned short* Vsrc = Vgb + (size_t)(kt+1)*8192;
      #pragma unroll
      for(int i=0;i<4;i++){ int c=i*256+tid; gl_lds16(Vsrc + c*8, &Vs[c*8]); }
    }
  }
  // epilogue: *w/l, write per-expert output [e][rank][h*128+d]
  #pragma unroll
  for(int r=0;r<4;r++){
    int qrank = qt*64 + w*16 + 4*g + r;
    float fac = sel_w[e*CAPN + qrank] / l_r[r];
    #pragma unroll
    for(int fd=0;fd<8;fd++){
      oexp[((size_t)(e*CAPN + qrank))*E_DIM + hh*DH + fd*16 + r16] = f2bf(o[fd][r]*fac);
    }
  }
}

// ---------------- scatter-accumulate over experts ----------------
__global__ __launch_bounds__(256) void acc_kernel(const unsigned short* __restrict__ oexp,
    const int* __restrict__ rank_of, unsigned short* __restrict__ accb){
  int n = blockIdx.x, t = threadIdx.x;
  int base = t*8;
  float s[8] = {0,0,0,0,0,0,0,0};
  #pragma unroll
  for(int e=0;e<4;e++){
    int r = rank_of[e*4096+n];
    if (r>=0){
      union{uint4 q; unsigned short u[8];} ld;
      ld.q = *(const uint4*)(oexp + ((size_t)(e*CAPN+r))*E_DIM + base);
      #pragma unroll
      for(int j2=0;j2<8;j2++) s[j2] += bf2f(ld.u[j2]);
    }
  }
  union{uint4 q; unsigned short u[8];} st;
  #pragma unroll
  for(int j2=0;j2<8;j2++) st.u[j2] = f2bf(s[j2]);
  *(uint4*)(accb + (size_t)n*E_DIM + base) = st.q;
}

// ---------------- launch ----------------
extern "C" void kernel_launch(void* const* d_in, const int* in_sizes, int n_in,
                              void* d_out, int out_size, void* d_ws, size_t ws_size,
                              hipStream_t stream) {
  const float* x   = (const float*)d_in[0];
  const float* Wq  = (const float*)d_in[1];
  const float* Wk  = (const float*)d_in[2];
  const float* Wv  = (const float*)d_in[3];
  const float* Wo  = (const float*)d_in[4];
  const float* Wr1 = (const float*)d_in[5];
  const float* br1 = (const float*)d_in[6];
  const float* Wr2 = (const float*)d_in[7];
  const float* br2 = (const float*)d_in[8];

  char* ws = (char*)d_ws;
  size_t off = 0;
  auto alloc = [&](size_t bytes)->void*{
    void* p = ws + off;
    off += (bytes + 255) & ~(size_t)255;
    return p;
  };
  unsigned short* xhi   = (unsigned short*)alloc((size_t)N_TOK*E_DIM*2);
  unsigned short* xlo   = (unsigned short*)alloc((size_t)N_TOK*E_DIM*2);
  unsigned short* wr1hi = (unsigned short*)alloc((size_t)E_DIM*1024*2);   // transposed [1024][2048]
  unsigned short* wr1lo = (unsigned short*)alloc((size_t)E_DIM*1024*2);
  unsigned short* wqkvT = (unsigned short*)alloc((size_t)3*E_DIM*E_DIM*2); // [6144][2048]
  unsigned short* woT   = (unsigned short*)alloc((size_t)E_DIM*E_DIM*2);
  void* hv = alloc((size_t)KEXP*NH*CAPN*DH*2);   // max(hbuf 16.8MB, Vg 21MB)
  float* hbuf = (float*)hv;                      // dead after scores_kernel
  unsigned short* Vg = (unsigned short*)hv;      // written by prev_kernel later
  float* scores = (float*)alloc((size_t)N_TOK*4*4);
  float* tokmax = (float*)alloc((size_t)N_TOK*4);
  int*   topkI  = (int*)alloc((size_t)KEXP*CAPN*4);
  float* selw   = (float*)alloc((size_t)KEXP*CAPN*4);
  int*   rankof = (int*)alloc((size_t)KEXP*N_TOK*4);
  float* cosT   = (float*)alloc((size_t)CAPN*64*4);
  float* sinT   = (float*)alloc((size_t)CAPN*64*4);
  unsigned short* qkvbuf = (unsigned short*)alloc((size_t)N_TOK*QKV_STRIDE*2);
  unsigned short* oexp = (unsigned short*)alloc((size_t)KEXP*CAPN*E_DIM*2);
  unsigned short* accb = (unsigned short*)alloc((size_t)N_TOK*E_DIM*2);
  if (off > ws_size) return;   // fail loudly (output stays poisoned)

  // Kg (21MB, swizzled) aliases xlo+wr1hi+wr1lo (25.2MB), dead after router GEMM
  unsigned short* Kg = xlo;

  // conversions
  conv_x_kernel<<<(N_TOK*E_DIM/4+255)/256, 256, 0, stream>>>(x, xhi, xlo, N_TOK*E_DIM/4);
  tconv_kernel<<<dim3(1024/32, E_DIM/32), dim3(32,8), 0, stream>>>(Wr1, wr1hi, wr1lo, E_DIM, 1024);
  tconv_kernel<<<dim3(E_DIM/32, E_DIM/32), dim3(32,8), 0, stream>>>(Wq, wqkvT,                nullptr, E_DIM, E_DIM);
  tconv_kernel<<<dim3(E_DIM/32, E_DIM/32), dim3(32,8), 0, stream>>>(Wk, wqkvT +   (size_t)E_DIM*E_DIM, nullptr, E_DIM, E_DIM);
  tconv_kernel<<<dim3(E_DIM/32, E_DIM/32), dim3(32,8), 0, stream>>>(Wv, wqkvT + (size_t)2*E_DIM*E_DIM, nullptr, E_DIM, E_DIM);
  tconv_kernel<<<dim3(E_DIM/32, E_DIM/32), dim3(32,8), 0, stream>>>(Wo, woT, nullptr, E_DIM, E_DIM);

  // fused router: H = gelu(x@Wr1 + br1) (hi/lo split, one pass)
  gemm_router_kernel<<<dim3(8, 32), 256, 0, stream>>>(xhi, xlo, wr1hi, wr1lo, br1, hbuf);
  scores_kernel<<<N_TOK/4, 256, 0, stream>>>(hbuf, Wr2, br2, scores, tokmax);
  aux_kernel<<<1, 1024, 0, stream>>>(tokmax, ((float*)d_out) + (size_t)N_TOK*E_DIM);
  topk_kernel<<<KEXP, 1024, 0, stream>>>(scores, topkI, selw, rankof);
  rope_kernel<<<CAPN*64/256, 256, 0, stream>>>(cosT, sinT);

  // fused QKV projection (bf16): [4096][6144]
  gemm_kernel<0,1><<<dim3(3*E_DIM/128, N_TOK/128), 256, 0, stream>>>(xhi, wqkvT, qkvbuf, QKV_STRIDE, E_DIM);

  // pre-gather/rope/transpose K,V into dense swizzled tiles
  prerope_k_kernel<<<KEXP*NH*CAPN*16/256, 256, 0, stream>>>(qkvbuf + E_DIM, topkI, cosT, sinT, Kg);
  prev_kernel<<<KEXP*NH*NTILE, 256, 0, stream>>>(qkvbuf + 2*E_DIM, topkI, Vg);

  // gathered causal attention
  attn_kernel<<<KEXP*NH*NTILE, 256, 0, stream>>>(qkvbuf, Kg, Vg, topkI, selw, cosT, sinT, oexp);

  // scatter-accumulate experts -> token rows
  acc_kernel<<<N_TOK, 256, 0, stream>>>(oexp, rankof, accb);

  // final projection -> d_out
  gemm_kernel<0,0><<<dim3(E_DIM/128, N_TOK/128), 256, 0, stream>>>(accb, woT, (float*)d_out, E_DIM, E_DIM);
}